// Round 11
// baseline (902.590 us; speedup 1.0000x reference)
//
#include <hip/hip_runtime.h>
#include <cmath>

#define Bsz 2048
#define Hsz 1024
#define NG  4096          // 4*Hsz gate columns
#define BM  128           // batch rows per block
#define BK  32            // k elements per K-tile
#define NKT 32            // K=1024 / 32
#define NBUF 3

typedef __attribute__((ext_vector_type(8))) short bf16x8;
typedef __attribute__((ext_vector_type(4))) float f32x4;

struct CellArgs {
  int ncells, b0;
  int joint[8];
  const short* hih[8];   // h_in hi (bf16), null => zero state
  const short* hil[8];   // h_in lo (kept for proj precision)
  const float* cin[8];   // c_in, null => zero
  short* hoh[8];
  short* hol[8];
  float* cout[8];
};

struct ProjArgs {
  int ncells, b0;
  int joint[8];
  const short* hh[8];
  const short* hl[8];
};

__device__ __forceinline__ float sigmoidf_(float x) {
  return 1.0f / (1.0f + __expf(-x));
}
__device__ __forceinline__ float fast_tanh(float x) {
  float ax = fabsf(x);
  float e = __expf(2.0f * ax);
  float t = 1.0f - 2.0f / (e + 1.0f);
  return copysignf(t, x);
}
__device__ __forceinline__ float bf2f(short b) {
  unsigned u = ((unsigned)(unsigned short)b) << 16;
  float f; __builtin_memcpy(&f, &u, 4); return f;
}
__device__ __forceinline__ short f2bf(float f) {
  unsigned u; __builtin_memcpy(&u, &f, 4);
  u += 0x7fffu + ((u >> 16) & 1u);
  return (short)(u >> 16);
}
__device__ __forceinline__ void gl_lds16(const void* g, void* l) {
  __builtin_amdgcn_global_load_lds(
      (const __attribute__((address_space(1))) unsigned int*)g,
      (__attribute__((address_space(3))) unsigned int*)l, 16, 0, 0);
}
template <int N> __device__ __forceinline__ void vmw() {
  asm volatile("s_waitcnt vmcnt(%0)" :: "n"(N) : "memory");
}
__device__ __forceinline__ void lgkm0() {
  asm volatile("s_waitcnt lgkmcnt(0)" ::: "memory");
  __builtin_amdgcn_sched_barrier(0);
}

// Fused LSTM cell, bf16 MFMA. Block tile 128m x 256n (64 hc x 4 gates),
// BK=32, 256 threads (4 waves, 2m x 2n), WAVE TILE 64m x 128n: 32 MFMA
// per 12 ds_read_b128 per tile (was 16:8) -> matrix pipe becomes the
// binding pipe (round-10 analysis: issue-port bound, MFMA 28%+VALU 43%).
// THREE-deep LDS ring (72 KB -> 2 blocks/CU), one barrier per K-tile,
// counted vmw<6> (6 gl_lds per stage per wave: 2 A + 4 B chunks).
// LDS slot rotation swizzle (slot = (kg + (row>>1)) & 3) — conflict-free
// (verified round 10: 1.47e7 -> 0). B rows ordered (wq, gate, hc16) so
// each lane holds all 4 gates of its (m,hc) pairs -> fused epilogue.
// gates ~= h_hi @ Whi (correction terms dropped; empirically zero delta).
__launch_bounds__(256, 2)
__global__ void cell_kernel(const float* __restrict__ p3d,
                            const short* __restrict__ Whi,
                            const float4* __restrict__ wb,
                            CellArgs A) {
  __shared__ short Atile[NBUF][BM * BK];       // 3 x 8 KB
  __shared__ short Btile[NBUF][2 * BM * BK];   // 3 x 16 KB
  __shared__ float xs[BM * 4];                 // 2 KB

  const int z = blockIdx.z;
  const short* __restrict__ hih = A.hih[z];
  const float* __restrict__ cin = A.cin[z];
  short* __restrict__ hoh = A.hoh[z];
  short* __restrict__ hol = A.hol[z];
  float* __restrict__ co  = A.cout[z];

  const int t = threadIdx.x;
  const int lane = t & 63;
  const int w = t >> 6;            // wave 0..3
  const int wm = w >> 1;           // m half (64 rows)
  const int wn = w & 1;            // n half (32 hc)
  const int m0 = blockIdx.x * BM;
  const int hc0 = blockIdx.y * 64;
  const int lc = lane & 15;
  const int kg = lane >> 4;        // 0..3 (8-elem k slot)

  // ---- staging constants: chunk = 16 rows x 32 elems = 1 KB (one wave op)
  // LDS[row][slot] holds k-group (slot - (row>>1)) & 3; dest stays linear.
  const int l2 = lane >> 2;                       // row in chunk (0..15)
  const int sslot = ((((lane & 3) - ((lane >> 3) & 3)) & 3) * 8);
  int aOff[2], bOff[4];
  #pragma unroll
  for (int j = 0; j < 2; ++j) {
    const int chunk = j * 4 + w;                  // 0..7
    aOff[j] = (m0 + chunk * 16 + l2) * Hsz + sslot;
  }
  #pragma unroll
  for (int j = 0; j < 4; ++j) {
    const int np = (j * 4 + w) * 16 + l2;         // B lds row 0..255
    const int wq = np >> 7;                       // n-half
    const int g  = (np >> 5) & 3;                 // gate
    const int h5 = np & 31;                       // hc within 32
    bOff[j] = (g * Hsz + hc0 + wq * 32 + h5) * Hsz + sslot;
  }

  // ---- x staging ----
  if (t < BM) {
    const float* p = p3d + ((size_t)(A.b0 + m0 + t) * 16 + A.joint[z]) * 3;
    xs[t * 4 + 0] = p[0];
    xs[t * 4 + 1] = p[1];
    xs[t * 4 + 2] = p[2];
  }
  __syncthreads();

  f32x4 acc[4][8];
  #pragma unroll
  for (int mf = 0; mf < 4; ++mf)
    #pragma unroll
    for (int nf = 0; nf < 8; ++nf) acc[mf][nf] = (f32x4){0.f, 0.f, 0.f, 0.f};

  const bool hasH = (hih != nullptr);

  auto stage = [&](int kt, int buf) {
    const int k0 = kt * BK;
    #pragma unroll
    for (int j = 0; j < 2; ++j)
      gl_lds16(hih + aOff[j] + k0, &Atile[buf][(j * 4 + w) * 512]);
    #pragma unroll
    for (int j = 0; j < 4; ++j)
      gl_lds16(Whi + bOff[j] + k0, &Btile[buf][(j * 4 + w) * 512]);
  };

  if (hasH) {
    // read-side slot rotation: (kg + (row>>1)) & 3 (frag bases are
    // multiples of 16 rows -> (row>>1)&3 == (lc>>1)&3).
    const int rslot = ((kg + (lc >> 1)) & 3) * 8;
    const int aRB = (wm * 64 + lc) * BK + rslot;
    const int bRB = (wn * 128 + lc) * BK + rslot;

    stage(0, 0);
    stage(1, 1);
    vmw<6>();                       // tile 0 landed
    __builtin_amdgcn_s_barrier();

    int rb = 0;                     // ring index of tile kt
    for (int kt = 0; kt < NKT; ++kt) {
      const int sb = (rb + 2 >= NBUF) ? rb + 2 - NBUF : rb + 2;
      if (kt + 2 < NKT) stage(kt + 2, sb);
      const short* Ab = &Atile[rb][0];
      const short* Bb = &Btile[rb][0];
      bf16x8 af[4], bf[8];
      #pragma unroll
      for (int mf = 0; mf < 4; ++mf)
        af[mf] = *(const bf16x8*)(Ab + aRB + mf * 512);
      #pragma unroll
      for (int nf = 0; nf < 8; ++nf)
        bf[nf] = *(const bf16x8*)(Bb + bRB + nf * 512);
      lgkm0();
      __builtin_amdgcn_s_setprio(1);
      #pragma unroll
      for (int mf = 0; mf < 4; ++mf)
        #pragma unroll
        for (int nf = 0; nf < 8; ++nf)
          acc[mf][nf] = __builtin_amdgcn_mfma_f32_16x16x32_bf16(
              af[mf], bf[nf], acc[mf][nf], 0, 0, 0);
      __builtin_amdgcn_s_setprio(0);
      if (kt + 2 < NKT) vmw<6>();   // stage(kt+1) landed
      else vmw<0>();
      __builtin_amdgcn_s_barrier();
      rb = (rb + 1 >= NBUF) ? 0 : rb + 1;
    }
  }

  // ---- epilogue: biases + x@Wih^T, gate math, write split-bf16 h + f32 c ----
  // Lane owns hc = hc0 + wn*32 + hcp*16 + lc for hcp in {0,1};
  // gate g of (m, hc[hcp]) lives in acc[mf][g*2+hcp].
  float4 wv[2][4];
  int hcl[2];
  #pragma unroll
  for (int hcp = 0; hcp < 2; ++hcp) {
    hcl[hcp] = hc0 + wn * 32 + hcp * 16 + lc;
    #pragma unroll
    for (int g = 0; g < 4; ++g) wv[hcp][g] = wb[g * Hsz + hcl[hcp]];
  }
  #pragma unroll
  for (int mf = 0; mf < 4; ++mf) {
    #pragma unroll
    for (int r = 0; r < 4; ++r) {
      const int ml = wm * 64 + mf * 16 + kg * 4 + r;
      const int m = m0 + ml;
      const float x0 = xs[ml * 4 + 0], x1 = xs[ml * 4 + 1], x2 = xs[ml * 4 + 2];
      #pragma unroll
      for (int hcp = 0; hcp < 2; ++hcp) {
        const int hc = hcl[hcp];
        float pre[4];
        #pragma unroll
        for (int g = 0; g < 4; ++g)
          pre[g] = acc[mf][g * 2 + hcp][r] + wv[hcp][g].w +
                   x0 * wv[hcp][g].x + x1 * wv[hcp][g].y + x2 * wv[hcp][g].z;
        const float ci = cin ? cin[(size_t)m * Hsz + hc] : 0.0f;
        const float c2 = sigmoidf_(pre[1]) * ci + sigmoidf_(pre[0]) * fast_tanh(pre[2]);
        const float h2 = sigmoidf_(pre[3]) * fast_tanh(c2);
        co[(size_t)m * Hsz + hc] = c2;
        const short hhi = f2bf(h2);
        hoh[(size_t)m * Hsz + hc] = hhi;
        hol[(size_t)m * Hsz + hc] = f2bf(h2 - bf2f(hhi));
      }
    }
  }
}

// Whh -> bf16 plane; wb[col] = {Wih[col][0..2], bih+bhh}.
__global__ void prep_kernel(const float* __restrict__ Whh,
                            const float* __restrict__ Wih,
                            const float* __restrict__ bih,
                            const float* __restrict__ bhh,
                            short* __restrict__ Whi,
                            float4* __restrict__ wb) {
  const int n4 = NG * Hsz / 4;
  int i = blockIdx.x * blockDim.x + threadIdx.x;
  for (; i < n4; i += gridDim.x * blockDim.x) {
    float4 wv = reinterpret_cast<const float4*>(Whh)[i];
    short4 hi;
    hi.x = f2bf(wv.x);
    hi.y = f2bf(wv.y);
    hi.z = f2bf(wv.z);
    hi.w = f2bf(wv.w);
    reinterpret_cast<short4*>(Whi)[i] = hi;
  }
  int c = blockIdx.x * blockDim.x + threadIdx.x;
  if (c < NG)
    wb[c] = make_float4(Wih[c * 3], Wih[c * 3 + 1], Wih[c * 3 + 2],
                        bih[c] + bhh[c]);
}

// merged = scale*(a + b [+ c]) in split-bf16 h and f32 c.
__global__ void merge_kernel(short* __restrict__ ohh, short* __restrict__ ohl,
                             float* __restrict__ oc,
                             const short* __restrict__ ahh, const short* __restrict__ ahl,
                             const float* __restrict__ ac,
                             const short* __restrict__ bhh, const short* __restrict__ bhl,
                             const float* __restrict__ bc,
                             const short* __restrict__ chh, const short* __restrict__ chl,
                             const float* __restrict__ cc,
                             float scale, int n4) {
  int i = blockIdx.x * blockDim.x + threadIdx.x;
  for (; i < n4; i += gridDim.x * blockDim.x) {
    short4 ah = reinterpret_cast<const short4*>(ahh)[i];
    short4 al = reinterpret_cast<const short4*>(ahl)[i];
    short4 bh = reinterpret_cast<const short4*>(bhh)[i];
    short4 bl = reinterpret_cast<const short4*>(bhl)[i];
    float h[4];
    h[0] = bf2f(ah.x) + bf2f(al.x) + bf2f(bh.x) + bf2f(bl.x);
    h[1] = bf2f(ah.y) + bf2f(al.y) + bf2f(bh.y) + bf2f(bl.y);
    h[2] = bf2f(ah.z) + bf2f(al.z) + bf2f(bh.z) + bf2f(bl.z);
    h[3] = bf2f(ah.w) + bf2f(al.w) + bf2f(bh.w) + bf2f(bl.w);
    float4 c = reinterpret_cast<const float4*>(ac)[i];
    float4 c2 = reinterpret_cast<const float4*>(bc)[i];
    c.x += c2.x; c.y += c2.y; c.z += c2.z; c.w += c2.w;
    if (chh != nullptr) {
      short4 ch = reinterpret_cast<const short4*>(chh)[i];
      short4 cl = reinterpret_cast<const short4*>(chl)[i];
      h[0] += bf2f(ch.x) + bf2f(cl.x);
      h[1] += bf2f(ch.y) + bf2f(cl.y);
      h[2] += bf2f(ch.z) + bf2f(cl.z);
      h[3] += bf2f(ch.w) + bf2f(cl.w);
      float4 c3 = reinterpret_cast<const float4*>(cc)[i];
      c.x += c3.x; c.y += c3.y; c.z += c3.z; c.w += c3.w;
    }
    short4 hi, lo;
    float v;
    v = h[0] * scale; hi.x = f2bf(v); lo.x = f2bf(v - bf2f(hi.x));
    v = h[1] * scale; hi.y = f2bf(v); lo.y = f2bf(v - bf2f(hi.y));
    v = h[2] * scale; hi.z = f2bf(v); lo.z = f2bf(v - bf2f(hi.z));
    v = h[3] * scale; hi.w = f2bf(v); lo.w = f2bf(v - bf2f(hi.w));
    reinterpret_cast<short4*>(ohh)[i] = hi;
    reinterpret_cast<short4*>(ohl)[i] = lo;
    c.x *= scale; c.y *= scale; c.z *= scale; c.w *= scale;
    reinterpret_cast<float4*>(oc)[i] = c;
  }
}

__global__ void init_out_kernel(float* __restrict__ out, const float* __restrict__ bref) {
  int i = blockIdx.x * blockDim.x + threadIdx.x;
  const int n = Bsz * 16 * 3;
  for (; i < n; i += gridDim.x * blockDim.x) out[i] = bref[i % 3];
}

// out[b0+b, joint, :] += 0.5 * h[b,:] @ Wref^T   (h = hi + lo, exact split)
__global__ void proj_kernel(ProjArgs P, const float* __restrict__ Wref,
                            float* __restrict__ out) {
  const int cell = blockIdx.x;
  const int b = blockIdx.y;
  const int t = threadIdx.x;
  const short4* hh = reinterpret_cast<const short4*>(P.hh[cell] + (size_t)b * Hsz);
  const short4* hl = reinterpret_cast<const short4*>(P.hl[cell] + (size_t)b * Hsz);
  const float4* W0 = reinterpret_cast<const float4*>(Wref);
  const float4* W1 = reinterpret_cast<const float4*>(Wref + Hsz);
  const float4* W2 = reinterpret_cast<const float4*>(Wref + 2 * Hsz);
  short4 a = hh[t], l = hl[t];
  float v0 = 0.5f * (bf2f(a.x) + bf2f(l.x));
  float v1 = 0.5f * (bf2f(a.y) + bf2f(l.y));
  float v2 = 0.5f * (bf2f(a.z) + bf2f(l.z));
  float v3 = 0.5f * (bf2f(a.w) + bf2f(l.w));
  float4 w0 = W0[t], w1 = W1[t], w2 = W2[t];
  float s0 = v0 * w0.x + v1 * w0.y + v2 * w0.z + v3 * w0.w;
  float s1 = v0 * w1.x + v1 * w1.y + v2 * w1.z + v3 * w1.w;
  float s2 = v0 * w2.x + v1 * w2.y + v2 * w2.z + v3 * w2.w;
  #pragma unroll
  for (int off = 32; off > 0; off >>= 1) {
    s0 += __shfl_down(s0, off);
    s1 += __shfl_down(s1, off);
    s2 += __shfl_down(s2, off);
  }
  __shared__ float red[4][3];
  const int wave = t >> 6;
  if ((t & 63) == 0) { red[wave][0] = s0; red[wave][1] = s1; red[wave][2] = s2; }
  __syncthreads();
  if (t == 0) {
    float r0 = red[0][0] + red[1][0] + red[2][0] + red[3][0];
    float r1 = red[0][1] + red[1][1] + red[2][1] + red[3][1];
    float r2 = red[0][2] + red[1][2] + red[2][2] + red[3][2];
    float* o = out + ((size_t)(P.b0 + b) * 16 + P.joint[cell]) * 3;
    atomicAdd(o + 0, r0);
    atomicAdd(o + 1, r1);
    atomicAdd(o + 2, r2);
  }
}

extern "C" void kernel_launch(void* const* d_in, const int* in_sizes, int n_in,
                              void* d_out, int out_size, void* d_ws, size_t ws_size,
                              hipStream_t stream) {
  const float* p3d  = (const float*)d_in[0];
  const float* Wih  = (const float*)d_in[1];
  const float* Whh  = (const float*)d_in[2];
  const float* bih  = (const float*)d_in[3];
  const float* bhh  = (const float*)d_in[4];
  const float* Wref = (const float*)d_in[5];
  const float* bref = (const float*)d_in[6];
  float* out = (float*)d_out;

  char* ws = (char*)d_ws;
  short* Whi = (short*)ws;                        // 8 MB
  float4* wb = (float4*)(Whi + (size_t)NG * Hsz); // 64 KB
  char* pool = (char*)(wb + NG);
  const size_t fixed = (size_t)(pool - ws);

  int chunkB = Bsz;
  while (chunkB > BM && fixed + (size_t)12 * chunkB * Hsz * 8 > ws_size)
    chunkB >>= 1;
  const size_t CH = (size_t)chunkB * Hsz;
  auto SH = [&](int s) { return (short*)(pool + (size_t)s * CH * 8); };
  auto SL = [&](int s) { return SH(s) + CH; };
  auto SC = [&](int s) { return (float*)(SL(s) + CH); };

  const dim3 blk(256);
  prep_kernel<<<dim3(4096), blk, 0, stream>>>(Whh, Wih, bih, bhh, Whi, wb);
  init_out_kernel<<<dim3(96), blk, 0, stream>>>(out, bref);

  for (int b0 = 0; b0 < Bsz; b0 += chunkB) {
    auto run_cells = [&](CellArgs& A) {
      A.b0 = b0;
      dim3 grid(chunkB / BM, Hsz / 64, A.ncells);
      cell_kernel<<<grid, blk, 0, stream>>>(p3d, Whi, wb, A);
    };
    auto run_proj = [&](ProjArgs& P) {
      P.b0 = b0;
      proj_kernel<<<dim3(P.ncells, chunkB), blk, 0, stream>>>(P, Wref, out);
    };
    auto cellset = [&](CellArgs& A, int i, int joint, int sin, int sout) {
      A.joint[i] = joint;
      if (sin >= 0) { A.hih[i] = SH(sin); A.hil[i] = SL(sin); A.cin[i] = SC(sin); }
      else          { A.hih[i] = nullptr; A.hil[i] = nullptr; A.cin[i] = nullptr; }
      A.hoh[i] = SH(sout); A.hol[i] = SL(sout); A.cout[i] = SC(sout);
    };
    auto projset = [&](ProjArgs& P, int i, int joint, int s) {
      P.joint[i] = joint; P.hh[i] = SH(s); P.hl[i] = SL(s);
    };
    auto domerge = [&](int dst, int s1, int s2, int s3, float scale) {
      merge_kernel<<<dim3(1024), blk, 0, stream>>>(
          SH(dst), SL(dst), SC(dst), SH(s1), SL(s1), SC(s1),
          SH(s2), SL(s2), SC(s2),
          s3 >= 0 ? SH(s3) : nullptr, s3 >= 0 ? SL(s3) : nullptr,
          s3 >= 0 ? SC(s3) : nullptr, scale, (int)(CH / 4));
    };

    { // L1: roots (zero state)
      CellArgs A{}; A.ncells = 5;
      cellset(A, 0, 15, -1, 0); cellset(A, 1, 10, -1, 1); cellset(A, 2, 5, -1, 2);
      cellset(A, 3,  0, -1, 3); cellset(A, 4,  9, -1, 4);
      run_cells(A);
      ProjArgs P{}; P.ncells = 5;
      projset(P, 0, 15, 0); projset(P, 1, 10, 1); projset(P, 2, 5, 2);
      projset(P, 3,  0, 3); projset(P, 4,  9, 4);
      run_proj(P);
    }
    { // L2
      CellArgs A{}; A.ncells = 5;
      cellset(A, 0, 14, 0, 5); cellset(A, 1, 11, 1, 6); cellset(A, 2, 4, 2, 7);
      cellset(A, 3,  1, 3, 8); cellset(A, 4,  8, 4, 9);
      run_cells(A);
      ProjArgs P{}; P.ncells = 5;
      projset(P, 0, 14, 5); projset(P, 1, 11, 6); projset(P, 2, 4, 7);
      projset(P, 3,  1, 8); projset(P, 4,  8, 9);
      run_proj(P);
    }
    { // L3
      CellArgs A{}; A.ncells = 7;
      cellset(A, 0, 13, 5, 0);  cellset(A, 1, 12, 6, 1);  cellset(A, 2, 3, 7, 2);
      cellset(A, 3,  2, 8, 3);  cellset(A, 4,  7, 9, 4);  cellset(A, 5, 13, 9, 10);
      cellset(A, 6, 12, 9, 11);
      run_cells(A);
      ProjArgs P{}; P.ncells = 7;
      projset(P, 0, 13, 0);  projset(P, 1, 12, 1);  projset(P, 2, 3, 2);
      projset(P, 3,  2, 3);  projset(P, 4,  7, 4);  projset(P, 5, 13, 10);
      projset(P, 6, 12, 11);
      run_proj(P);
    }
    domerge(5, 3, 2, -1, 0.5f);                 // m = (f2 + f3)/2
    { // L4
      CellArgs A{}; A.ncells = 4;
      cellset(A, 0,  6, 5, 6);  cellset(A, 1,  6, 4, 7);
      cellset(A, 2, 14, 10, 8); cellset(A, 3, 11, 11, 9);
      run_cells(A);
      ProjArgs P{}; P.ncells = 4;
      projset(P, 0, 6, 6); projset(P, 1, 6, 7); projset(P, 2, 14, 8);
      projset(P, 3, 11, 9);
      run_proj(P);
    }
    { // L5
      CellArgs A{}; A.ncells = 5;
      cellset(A, 0,  7, 6, 4);  cellset(A, 1, 15, 8, 5);  cellset(A, 2, 10, 9, 10);
      cellset(A, 3,  3, 7, 11); cellset(A, 4,  2, 7, 2);
      run_cells(A);
      ProjArgs P{}; P.ncells = 5;
      projset(P, 0, 7, 4);  projset(P, 1, 15, 5); projset(P, 2, 10, 10);
      projset(P, 3, 3, 11); projset(P, 4,  2, 2);
      run_proj(P);
    }
    domerge(6, 4, 0, 1, 1.0f / 3.0f);           // m2 = (f7 + f13 + f12)/3
    { // L6
      CellArgs A{}; A.ncells = 3;
      cellset(A, 0, 8, 6, 0); cellset(A, 1, 4, 11, 1); cellset(A, 2, 1, 2, 3);
      run_cells(A);
      ProjArgs P{}; P.ncells = 3;
      projset(P, 0, 8, 0); projset(P, 1, 4, 1); projset(P, 2, 1, 3);
      run_proj(P);
    }
    { // L7
      CellArgs A{}; A.ncells = 3;
      cellset(A, 0, 9, 0, 2); cellset(A, 1, 5, 1, 4); cellset(A, 2, 0, 3, 5);
      run_cells(A);
      ProjArgs P{}; P.ncells = 3;
      projset(P, 0, 9, 2); projset(P, 1, 5, 4); projset(P, 2, 0, 5);
      run_proj(P);
    }
  }
}

// Round 12
// 894.914 us; speedup vs baseline: 1.0086x; 1.0086x over previous
//
#include <hip/hip_runtime.h>
#include <cmath>

#define Bsz 2048
#define Hsz 1024
#define NG  4096          // 4*Hsz gate columns
#define BM  128           // batch rows per block
#define BK  32            // k elements per K-tile
#define NKT 32            // K=1024 / 32
#define NBUF 3

typedef __attribute__((ext_vector_type(8))) short bf16x8;
typedef __attribute__((ext_vector_type(4))) float f32x4;

struct CellArgs {
  int ncells, b0;
  int joint[8];
  const short* hih[8];   // h_in hi (bf16), null => zero state
  const short* hil[8];   // h_in lo (kept for proj precision)
  const float* cin[8];   // c_in, null => zero
  short* hoh[8];
  short* hol[8];
  float* cout[8];        // null => terminal cell (c never read)
};

struct ProjArgs {
  int ncells, b0;
  int joint[8];
  const short* hh[8];
  const short* hl[8];
};

__device__ __forceinline__ float sigmoidf_(float x) {
  return 1.0f / (1.0f + __expf(-x));
}
__device__ __forceinline__ float fast_tanh(float x) {
  float ax = fabsf(x);
  float e = __expf(2.0f * ax);
  float t = 1.0f - 2.0f / (e + 1.0f);
  return copysignf(t, x);
}
__device__ __forceinline__ float bf2f(short b) {
  unsigned u = ((unsigned)(unsigned short)b) << 16;
  float f; __builtin_memcpy(&f, &u, 4); return f;
}
__device__ __forceinline__ short f2bf(float f) {
  unsigned u; __builtin_memcpy(&u, &f, 4);
  u += 0x7fffu + ((u >> 16) & 1u);
  return (short)(u >> 16);
}
__device__ __forceinline__ void gl_lds16(const void* g, void* l) {
  __builtin_amdgcn_global_load_lds(
      (const __attribute__((address_space(1))) unsigned int*)g,
      (__attribute__((address_space(3))) unsigned int*)l, 16, 0, 0);
}
template <int N> __device__ __forceinline__ void vmw() {
  asm volatile("s_waitcnt vmcnt(%0)" :: "n"(N) : "memory");
}
__device__ __forceinline__ void lgkm0() {
  asm volatile("s_waitcnt lgkmcnt(0)" ::: "memory");
  __builtin_amdgcn_sched_barrier(0);
}

// Fused LSTM cell, bf16 MFMA. 128m x 128n (32 hc x 4 gates) tile, BK=32,
// 256 threads (4 waves, 2x2), THREE-deep LDS ring, 3 blocks/CU.
// ROUND-12 CHANGE: register fragment double-buffer. Per tile kt:
//   ds_read frags(kt+1)          (latency hides under MFMA below)
//   stage(kt+3) -> buf[kt%3]     (tile kt's frags consumed at kt-1; safe)
//   MFMA with frags(kt)          (already in regs)
//   lgkm0                        (trivially satisfied now)
//   vmw<6>                       (stage(kt+2) landed; counted, not drained)
//   barrier
// This removes the lgkm0-before-MFMA wall that pinned MfmaUtil at ~28%
// across R9-R11 (waits now post-overlap). Loop unrolled x2 so frag
// buffers have compile-time indices (no scratch). MFMA order unchanged
// -> bit-identical numerics. Conflict-free slot rotation swizzle (R10).
// gates ~= h_hi @ Whi (correction terms dropped; empirically zero delta).
__launch_bounds__(256, 3)
__global__ void cell_kernel(const float* __restrict__ p3d,
                            const short* __restrict__ Whi,
                            const float4* __restrict__ wb,
                            CellArgs A) {
  __shared__ short Atile[NBUF][BM * BK];   // 3 x 8 KB
  __shared__ short Btile[NBUF][BM * BK];   // 3 x 8 KB
  __shared__ float xs[BM * 4];             // 2 KB

  const int z = blockIdx.z;
  const short* __restrict__ hih = A.hih[z];
  const float* __restrict__ cin = A.cin[z];
  short* __restrict__ hoh = A.hoh[z];
  short* __restrict__ hol = A.hol[z];
  float* __restrict__ co  = A.cout[z];

  const int t = threadIdx.x;
  const int lane = t & 63;
  const int w = t >> 6;            // wave 0..3
  const int wm = w >> 1;           // m half (64 rows)
  const int wn = w & 1;            // n half (16 hc)
  const int m0 = blockIdx.x * BM;
  const int hc0 = blockIdx.y * 32;
  const int lc = lane & 15;
  const int kg = lane >> 4;        // 0..3 (8-elem k slot)

  // ---- staging constants: chunk = 16 rows x 32 elems = 1 KB (one wave op)
  // LDS[row][slot] holds k-group (slot - (row>>1)) & 3; dest stays linear.
  const int l2 = lane >> 2;                       // row in chunk (0..15)
  const int sslot = ((((lane & 3) - ((lane >> 3) & 3)) & 3) * 8);
  int aOff[2], bOff[2];
  #pragma unroll
  for (int j = 0; j < 2; ++j) {
    const int chunk = j * 4 + w;                  // 0..7
    aOff[j] = (m0 + chunk * 16 + l2) * Hsz + sslot;
    const int np = chunk * 16 + l2;               // B lds row 0..127
    const int g = np >> 5;                        // gate
    const int hcl = np & 31;
    bOff[j] = (g * Hsz + hc0 + hcl) * Hsz + sslot;
  }

  // ---- x staging ----
  if (t < BM) {
    const float* p = p3d + ((size_t)(A.b0 + m0 + t) * 16 + A.joint[z]) * 3;
    xs[t * 4 + 0] = p[0];
    xs[t * 4 + 1] = p[1];
    xs[t * 4 + 2] = p[2];
  }
  __syncthreads();

  f32x4 acc[4][4];
  #pragma unroll
  for (int mf = 0; mf < 4; ++mf)
    #pragma unroll
    for (int nf = 0; nf < 4; ++nf) acc[mf][nf] = (f32x4){0.f, 0.f, 0.f, 0.f};

  const bool hasH = (hih != nullptr);

  auto stage = [&](int kt, int buf) {
    const int k0 = kt * BK;
    #pragma unroll
    for (int j = 0; j < 2; ++j)
      gl_lds16(hih + aOff[j] + k0, &Atile[buf][(j * 4 + w) * 512]);
    #pragma unroll
    for (int j = 0; j < 2; ++j)
      gl_lds16(Whi + bOff[j] + k0, &Btile[buf][(j * 4 + w) * 512]);
  };

  if (hasH) {
    // read-side slot rotation: (kg + (row>>1)) & 3 (frag bases are
    // multiples of 16 rows -> (row>>1)&3 == (lc>>1)&3).
    const int rslot = ((kg + (lc >> 1)) & 3) * 8;
    const int aRB = (wm * 64 + lc) * BK + rslot;
    const int bRB = (wn * 16 + lc) * BK + rslot;

    stage(0, 0);
    stage(1, 1);
    stage(2, 2);
    vmw<6>();                       // tiles 0 AND 1 landed
    __builtin_amdgcn_s_barrier();

    bf16x8 fa0[4], fb0[4], fa1[4], fb1[4];
    #pragma unroll
    for (int i = 0; i < 4; ++i) {   // preload frags(0)
      fa0[i] = *(const bf16x8*)(&Atile[0][0] + aRB + i * 512);
      fb0[i] = *(const bf16x8*)(&Btile[0][0] + bRB + i * 1024);
    }

    int rb = 0;                     // ring index of current tile
    for (int kt = 0; kt < NKT; kt += 2) {
      { // ---- even tile kt: cur frags = f*0, prefetch -> f*1 ----
        const int rn = (rb + 1 >= NBUF) ? 0 : rb + 1;
        if (kt + 1 < NKT) {
          #pragma unroll
          for (int i = 0; i < 4; ++i) {
            fa1[i] = *(const bf16x8*)(&Atile[rn][0] + aRB + i * 512);
            fb1[i] = *(const bf16x8*)(&Btile[rn][0] + bRB + i * 1024);
          }
        }
        if (kt + 3 < NKT) stage(kt + 3, rb);
        __builtin_amdgcn_s_setprio(1);
        #pragma unroll
        for (int mf = 0; mf < 4; ++mf)
          #pragma unroll
          for (int nf = 0; nf < 4; ++nf)
            acc[mf][nf] = __builtin_amdgcn_mfma_f32_16x16x32_bf16(
                fa0[mf], fb0[nf], acc[mf][nf], 0, 0, 0);
        __builtin_amdgcn_s_setprio(0);
        lgkm0();                    // prefetched frags retired (overlapped)
        if (kt + 3 < NKT) vmw<6>(); // stage(kt+2) landed
        else vmw<0>();
        __builtin_amdgcn_s_barrier();
        rb = rn;
      }
      { // ---- odd tile kt+1: cur frags = f*1, prefetch -> f*0 ----
        const int ko = kt + 1;
        const int rn = (rb + 1 >= NBUF) ? 0 : rb + 1;
        if (ko + 1 < NKT) {
          #pragma unroll
          for (int i = 0; i < 4; ++i) {
            fa0[i] = *(const bf16x8*)(&Atile[rn][0] + aRB + i * 512);
            fb0[i] = *(const bf16x8*)(&Btile[rn][0] + bRB + i * 1024);
          }
        }
        if (ko + 3 < NKT) stage(ko + 3, rb);
        __builtin_amdgcn_s_setprio(1);
        #pragma unroll
        for (int mf = 0; mf < 4; ++mf)
          #pragma unroll
          for (int nf = 0; nf < 4; ++nf)
            acc[mf][nf] = __builtin_amdgcn_mfma_f32_16x16x32_bf16(
                fa1[mf], fb1[nf], acc[mf][nf], 0, 0, 0);
        __builtin_amdgcn_s_setprio(0);
        lgkm0();
        if (ko + 3 < NKT) vmw<6>();
        else vmw<0>();
        __builtin_amdgcn_s_barrier();
        rb = rn;
      }
    }
  }

  // ---- epilogue: biases + x@Wih^T, gate math, write split-bf16 h + f32 c ----
  const int hc = hc0 + wn * 16 + lc;
  float4 wv[4];
  #pragma unroll
  for (int g = 0; g < 4; ++g) wv[g] = wb[g * Hsz + hc];
  #pragma unroll
  for (int mf = 0; mf < 4; ++mf) {
    #pragma unroll
    for (int r = 0; r < 4; ++r) {
      const int ml = wm * 64 + mf * 16 + kg * 4 + r;
      const int m = m0 + ml;
      const float x0 = xs[ml * 4 + 0], x1 = xs[ml * 4 + 1], x2 = xs[ml * 4 + 2];
      float pre[4];
      #pragma unroll
      for (int g = 0; g < 4; ++g)
        pre[g] = acc[mf][g][r] + wv[g].w + x0 * wv[g].x + x1 * wv[g].y + x2 * wv[g].z;
      const float ci = cin ? cin[(size_t)m * Hsz + hc] : 0.0f;
      const float c2 = sigmoidf_(pre[1]) * ci + sigmoidf_(pre[0]) * fast_tanh(pre[2]);
      const float h2 = sigmoidf_(pre[3]) * fast_tanh(c2);
      if (co) co[(size_t)m * Hsz + hc] = c2;
      const short hhi = f2bf(h2);
      hoh[(size_t)m * Hsz + hc] = hhi;
      hol[(size_t)m * Hsz + hc] = f2bf(h2 - bf2f(hhi));
    }
  }
}

// Whh -> bf16 plane; wb[col] = {Wih[col][0..2], bih+bhh}.
__global__ void prep_kernel(const float* __restrict__ Whh,
                            const float* __restrict__ Wih,
                            const float* __restrict__ bih,
                            const float* __restrict__ bhh,
                            short* __restrict__ Whi,
                            float4* __restrict__ wb) {
  const int n4 = NG * Hsz / 4;
  int i = blockIdx.x * blockDim.x + threadIdx.x;
  for (; i < n4; i += gridDim.x * blockDim.x) {
    float4 wv = reinterpret_cast<const float4*>(Whh)[i];
    short4 hi;
    hi.x = f2bf(wv.x);
    hi.y = f2bf(wv.y);
    hi.z = f2bf(wv.z);
    hi.w = f2bf(wv.w);
    reinterpret_cast<short4*>(Whi)[i] = hi;
  }
  int c = blockIdx.x * blockDim.x + threadIdx.x;
  if (c < NG)
    wb[c] = make_float4(Wih[c * 3], Wih[c * 3 + 1], Wih[c * 3 + 2],
                        bih[c] + bhh[c]);
}

// merged = scale*(a + b [+ c]) in split-bf16 h and f32 c.
__global__ void merge_kernel(short* __restrict__ ohh, short* __restrict__ ohl,
                             float* __restrict__ oc,
                             const short* __restrict__ ahh, const short* __restrict__ ahl,
                             const float* __restrict__ ac,
                             const short* __restrict__ bhh, const short* __restrict__ bhl,
                             const float* __restrict__ bc,
                             const short* __restrict__ chh, const short* __restrict__ chl,
                             const float* __restrict__ cc,
                             float scale, int n4) {
  int i = blockIdx.x * blockDim.x + threadIdx.x;
  for (; i < n4; i += gridDim.x * blockDim.x) {
    short4 ah = reinterpret_cast<const short4*>(ahh)[i];
    short4 al = reinterpret_cast<const short4*>(ahl)[i];
    short4 bh = reinterpret_cast<const short4*>(bhh)[i];
    short4 bl = reinterpret_cast<const short4*>(bhl)[i];
    float h[4];
    h[0] = bf2f(ah.x) + bf2f(al.x) + bf2f(bh.x) + bf2f(bl.x);
    h[1] = bf2f(ah.y) + bf2f(al.y) + bf2f(bh.y) + bf2f(bl.y);
    h[2] = bf2f(ah.z) + bf2f(al.z) + bf2f(bh.z) + bf2f(bl.z);
    h[3] = bf2f(ah.w) + bf2f(al.w) + bf2f(bh.w) + bf2f(bl.w);
    float4 c = reinterpret_cast<const float4*>(ac)[i];
    float4 c2 = reinterpret_cast<const float4*>(bc)[i];
    c.x += c2.x; c.y += c2.y; c.z += c2.z; c.w += c2.w;
    if (chh != nullptr) {
      short4 ch = reinterpret_cast<const short4*>(chh)[i];
      short4 cl = reinterpret_cast<const short4*>(chl)[i];
      h[0] += bf2f(ch.x) + bf2f(cl.x);
      h[1] += bf2f(ch.y) + bf2f(cl.y);
      h[2] += bf2f(ch.z) + bf2f(cl.z);
      h[3] += bf2f(ch.w) + bf2f(cl.w);
      float4 c3 = reinterpret_cast<const float4*>(cc)[i];
      c.x += c3.x; c.y += c3.y; c.z += c3.z; c.w += c3.w;
    }
    short4 hi, lo;
    float v;
    v = h[0] * scale; hi.x = f2bf(v); lo.x = f2bf(v - bf2f(hi.x));
    v = h[1] * scale; hi.y = f2bf(v); lo.y = f2bf(v - bf2f(hi.y));
    v = h[2] * scale; hi.z = f2bf(v); lo.z = f2bf(v - bf2f(hi.z));
    v = h[3] * scale; hi.w = f2bf(v); lo.w = f2bf(v - bf2f(hi.w));
    reinterpret_cast<short4*>(ohh)[i] = hi;
    reinterpret_cast<short4*>(ohl)[i] = lo;
    c.x *= scale; c.y *= scale; c.z *= scale; c.w *= scale;
    reinterpret_cast<float4*>(oc)[i] = c;
  }
}

__global__ void init_out_kernel(float* __restrict__ out, const float* __restrict__ bref) {
  int i = blockIdx.x * blockDim.x + threadIdx.x;
  const int n = Bsz * 16 * 3;
  for (; i < n; i += gridDim.x * blockDim.x) out[i] = bref[i % 3];
}

// out[b0+b, joint, :] += 0.5 * h[b,:] @ Wref^T   (h = hi + lo, exact split)
__global__ void proj_kernel(ProjArgs P, const float* __restrict__ Wref,
                            float* __restrict__ out) {
  const int cell = blockIdx.x;
  const int b = blockIdx.y;
  const int t = threadIdx.x;
  const short4* hh = reinterpret_cast<const short4*>(P.hh[cell] + (size_t)b * Hsz);
  const short4* hl = reinterpret_cast<const short4*>(P.hl[cell] + (size_t)b * Hsz);
  const float4* W0 = reinterpret_cast<const float4*>(Wref);
  const float4* W1 = reinterpret_cast<const float4*>(Wref + Hsz);
  const float4* W2 = reinterpret_cast<const float4*>(Wref + 2 * Hsz);
  short4 a = hh[t], l = hl[t];
  float v0 = 0.5f * (bf2f(a.x) + bf2f(l.x));
  float v1 = 0.5f * (bf2f(a.y) + bf2f(l.y));
  float v2 = 0.5f * (bf2f(a.z) + bf2f(l.z));
  float v3 = 0.5f * (bf2f(a.w) + bf2f(l.w));
  float4 w0 = W0[t], w1 = W1[t], w2 = W2[t];
  float s0 = v0 * w0.x + v1 * w0.y + v2 * w0.z + v3 * w0.w;
  float s1 = v0 * w1.x + v1 * w1.y + v2 * w1.z + v3 * w1.w;
  float s2 = v0 * w2.x + v1 * w2.y + v2 * w2.z + v3 * w2.w;
  #pragma unroll
  for (int off = 32; off > 0; off >>= 1) {
    s0 += __shfl_down(s0, off);
    s1 += __shfl_down(s1, off);
    s2 += __shfl_down(s2, off);
  }
  __shared__ float red[4][3];
  const int wave = t >> 6;
  if ((t & 63) == 0) { red[wave][0] = s0; red[wave][1] = s1; red[wave][2] = s2; }
  __syncthreads();
  if (t == 0) {
    float r0 = red[0][0] + red[1][0] + red[2][0] + red[3][0];
    float r1 = red[0][1] + red[1][1] + red[2][1] + red[3][1];
    float r2 = red[0][2] + red[1][2] + red[2][2] + red[3][2];
    float* o = out + ((size_t)(P.b0 + b) * 16 + P.joint[cell]) * 3;
    atomicAdd(o + 0, r0);
    atomicAdd(o + 1, r1);
    atomicAdd(o + 2, r2);
  }
}

extern "C" void kernel_launch(void* const* d_in, const int* in_sizes, int n_in,
                              void* d_out, int out_size, void* d_ws, size_t ws_size,
                              hipStream_t stream) {
  const float* p3d  = (const float*)d_in[0];
  const float* Wih  = (const float*)d_in[1];
  const float* Whh  = (const float*)d_in[2];
  const float* bih  = (const float*)d_in[3];
  const float* bhh  = (const float*)d_in[4];
  const float* Wref = (const float*)d_in[5];
  const float* bref = (const float*)d_in[6];
  float* out = (float*)d_out;

  char* ws = (char*)d_ws;
  short* Whi = (short*)ws;                        // 8 MB
  float4* wb = (float4*)(Whi + (size_t)NG * Hsz); // 64 KB
  char* pool = (char*)(wb + NG);
  const size_t fixed = (size_t)(pool - ws);

  int chunkB = Bsz;
  while (chunkB > BM && fixed + (size_t)12 * chunkB * Hsz * 8 > ws_size)
    chunkB >>= 1;
  const size_t CH = (size_t)chunkB * Hsz;
  auto SH = [&](int s) { return (short*)(pool + (size_t)s * CH * 8); };
  auto SL = [&](int s) { return SH(s) + CH; };
  auto SC = [&](int s) { return (float*)(SL(s) + CH); };

  const dim3 blk(256);
  prep_kernel<<<dim3(4096), blk, 0, stream>>>(Whh, Wih, bih, bhh, Whi, wb);
  init_out_kernel<<<dim3(96), blk, 0, stream>>>(out, bref);

  for (int b0 = 0; b0 < Bsz; b0 += chunkB) {
    auto run_cells = [&](CellArgs& A) {
      A.b0 = b0;
      dim3 grid(chunkB / BM, Hsz / 32, A.ncells);
      cell_kernel<<<grid, blk, 0, stream>>>(p3d, Whi, wb, A);
    };
    auto run_proj = [&](ProjArgs& P) {
      P.b0 = b0;
      proj_kernel<<<dim3(P.ncells, chunkB), blk, 0, stream>>>(P, Wref, out);
    };
    auto cellset = [&](CellArgs& A, int i, int joint, int sin, int sout,
                       bool cstore = true) {
      A.joint[i] = joint;
      if (sin >= 0) { A.hih[i] = SH(sin); A.hil[i] = SL(sin); A.cin[i] = SC(sin); }
      else          { A.hih[i] = nullptr; A.hil[i] = nullptr; A.cin[i] = nullptr; }
      A.hoh[i] = SH(sout); A.hol[i] = SL(sout);
      A.cout[i] = cstore ? SC(sout) : nullptr;
    };
    auto projset = [&](ProjArgs& P, int i, int joint, int s) {
      P.joint[i] = joint; P.hh[i] = SH(s); P.hl[i] = SL(s);
    };
    auto domerge = [&](int dst, int s1, int s2, int s3, float scale) {
      merge_kernel<<<dim3(1024), blk, 0, stream>>>(
          SH(dst), SL(dst), SC(dst), SH(s1), SL(s1), SC(s1),
          SH(s2), SL(s2), SC(s2),
          s3 >= 0 ? SH(s3) : nullptr, s3 >= 0 ? SL(s3) : nullptr,
          s3 >= 0 ? SC(s3) : nullptr, scale, (int)(CH / 4));
    };

    { // L1: roots (zero state)
      CellArgs A{}; A.ncells = 5;
      cellset(A, 0, 15, -1, 0); cellset(A, 1, 10, -1, 1); cellset(A, 2, 5, -1, 2);
      cellset(A, 3,  0, -1, 3); cellset(A, 4,  9, -1, 4);
      run_cells(A);
      ProjArgs P{}; P.ncells = 5;
      projset(P, 0, 15, 0); projset(P, 1, 10, 1); projset(P, 2, 5, 2);
      projset(P, 3,  0, 3); projset(P, 4,  9, 4);
      run_proj(P);
    }
    { // L2
      CellArgs A{}; A.ncells = 5;
      cellset(A, 0, 14, 0, 5); cellset(A, 1, 11, 1, 6); cellset(A, 2, 4, 2, 7);
      cellset(A, 3,  1, 3, 8); cellset(A, 4,  8, 4, 9);
      run_cells(A);
      ProjArgs P{}; P.ncells = 5;
      projset(P, 0, 14, 5); projset(P, 1, 11, 6); projset(P, 2, 4, 7);
      projset(P, 3,  1, 8); projset(P, 4,  8, 9);
      run_proj(P);
    }
    { // L3
      CellArgs A{}; A.ncells = 7;
      cellset(A, 0, 13, 5, 0);  cellset(A, 1, 12, 6, 1);  cellset(A, 2, 3, 7, 2);
      cellset(A, 3,  2, 8, 3);  cellset(A, 4,  7, 9, 4);  cellset(A, 5, 13, 9, 10);
      cellset(A, 6, 12, 9, 11);
      run_cells(A);
      ProjArgs P{}; P.ncells = 7;
      projset(P, 0, 13, 0);  projset(P, 1, 12, 1);  projset(P, 2, 3, 2);
      projset(P, 3,  2, 3);  projset(P, 4,  7, 4);  projset(P, 5, 13, 10);
      projset(P, 6, 12, 11);
      run_proj(P);
    }
    domerge(5, 3, 2, -1, 0.5f);                 // m = (f2 + f3)/2
    { // L4
      CellArgs A{}; A.ncells = 4;
      cellset(A, 0,  6, 5, 6);  cellset(A, 1,  6, 4, 7);
      cellset(A, 2, 14, 10, 8); cellset(A, 3, 11, 11, 9);
      run_cells(A);
      ProjArgs P{}; P.ncells = 4;
      projset(P, 0, 6, 6); projset(P, 1, 6, 7); projset(P, 2, 14, 8);
      projset(P, 3, 11, 9);
      run_proj(P);
    }
    { // L5 (b15, b10 terminal: c never read)
      CellArgs A{}; A.ncells = 5;
      cellset(A, 0,  7, 6, 4);         cellset(A, 1, 15, 8, 5, false);
      cellset(A, 2, 10, 9, 10, false); cellset(A, 3,  3, 7, 11);
      cellset(A, 4,  2, 7, 2);
      run_cells(A);
      ProjArgs P{}; P.ncells = 5;
      projset(P, 0, 7, 4);  projset(P, 1, 15, 5); projset(P, 2, 10, 10);
      projset(P, 3, 3, 11); projset(P, 4,  2, 2);
      run_proj(P);
    }
    domerge(6, 4, 0, 1, 1.0f / 3.0f);           // m2 = (f7 + f13 + f12)/3
    { // L6
      CellArgs A{}; A.ncells = 3;
      cellset(A, 0, 8, 6, 0); cellset(A, 1, 4, 11, 1); cellset(A, 2, 1, 2, 3);
      run_cells(A);
      ProjArgs P{}; P.ncells = 3;
      projset(P, 0, 8, 0); projset(P, 1, 4, 1); projset(P, 2, 1, 3);
      run_proj(P);
    }
    { // L7 (all terminal: c never read)
      CellArgs A{}; A.ncells = 3;
      cellset(A, 0, 9, 0, 2, false); cellset(A, 1, 5, 1, 4, false);
      cellset(A, 2, 0, 3, 5, false);
      run_cells(A);
      ProjArgs P{}; P.ncells = 3;
      projset(P, 0, 9, 2); projset(P, 1, 5, 4); projset(P, 2, 0, 5);
      run_proj(P);
    }
  }
}